// Round 1
// 402.409 us; speedup vs baseline: 1.0121x; 1.0121x over previous
//
#include <hip/hip_runtime.h>
#include <hip/hip_bf16.h>

// BNN MC-prediction: S=100 weight samples, batch 64, dims 784->512->512->10.
// R4: K-split x2 -> 2 waves per block (128 threads), same 1600-block grid.
// rocprof R3 showed the classic latency-bound signature (MfmaUtil 2%,
// VALUBusy 11%, HBM 11%, Occupancy 12%): 1600 waves over 1024 SIMDs with a
// 2-deep pipeline cannot hide ~900cy load latency. Doubling resident waves
// via K-split keeps eps read-exactly-once and keeps VGPR<=128 (4 waves/SIMD
// cap). Waves combine partials through a padded LDS buffer (one barrier),
// wave 0 does bias+relu+store. Main loop stays barrier-free per wave.

typedef __bf16 bf16x8 __attribute__((ext_vector_type(8)));
typedef float f32x4 __attribute__((ext_vector_type(4)));

#define NSAMP 100
#define BATCH 64
#define D0 784
#define D1 512
#define D2 512
#define DOUT 10
#define K0PAD 800   // 784 padded to multiple of 32 (A side zero-padded)
#define RSB 40      // smB row stride in shorts (80 B rows: 16B-aligned, spread banks)
#define PS 72       // psum row stride in floats (288 B: 16B-aligned, 4-way max on b128)

__device__ __forceinline__ unsigned short f2bf(float f) {
    __bf16 b = (__bf16)f;
    return __builtin_bit_cast(unsigned short, b);
}
// packed dword: high16 = bf16(sigma), low16 = bf16(mean)
__device__ __forceinline__ float bf_hi(unsigned int u) {
    return __builtin_bit_cast(float, u & 0xffff0000u);
}
__device__ __forceinline__ float bf_lo(unsigned int u) {
    return __builtin_bit_cast(float, u << 16);
}

union FragU { uint4 q; bf16x8 v; };

// ---------------- precompute ----------------
#define XB_N   (BATCH * K0PAD)
#define PS0_N  (D0 * D1)
#define PS1_N  (D1 * D2)
#define SGL_N  (D2 * DOUT)
#define B0_N   (NSAMP * D1)
#define B1_N   (NSAMP * D2)
#define BL_N   (NSAMP * DOUT)
#define PREP_TOTAL (XB_N + PS0_N + PS1_N + SGL_N + B0_N + B1_N + BL_N)

__global__ __launch_bounds__(256) void prep(
    const float* __restrict__ inputs,
    const float* __restrict__ wv0, const float* __restrict__ wm0,
    const float* __restrict__ wv1, const float* __restrict__ wm1,
    const float* __restrict__ wvl,
    const float* __restrict__ be0, const float* __restrict__ bv0, const float* __restrict__ bm0,
    const float* __restrict__ be1, const float* __restrict__ bv1, const float* __restrict__ bm1,
    const float* __restrict__ bel, const float* __restrict__ bvl, const float* __restrict__ bml,
    unsigned short* __restrict__ Xb,
    unsigned int* __restrict__ psm0, unsigned int* __restrict__ psm1,
    float* __restrict__ sigmal,
    float* __restrict__ bias0, float* __restrict__ bias1, float* __restrict__ biasl)
{
    int i = blockIdx.x * 256 + threadIdx.x;
    if (i < XB_N) {
        int m = i / K0PAD, k = i % K0PAD;
        float v = (k < D0) ? inputs[m * D0 + k] : 0.f;
        Xb[i] = f2bf(v);
        return;
    }
    i -= XB_N;
    if (i < PS0_N) {
        unsigned int sg = f2bf(__expf(0.5f * wv0[i]));
        unsigned int mn = f2bf(wm0[i]);
        psm0[i] = (sg << 16) | mn;
        return;
    }
    i -= PS0_N;
    if (i < PS1_N) {
        unsigned int sg = f2bf(__expf(0.5f * wv1[i]));
        unsigned int mn = f2bf(wm1[i]);
        psm1[i] = (sg << 16) | mn;
        return;
    }
    i -= PS1_N;
    if (i < SGL_N) { sigmal[i] = __expf(0.5f * wvl[i]); return; }
    i -= SGL_N;
    if (i < B0_N) { int n = i % D1; bias0[i] = fmaf(be0[i], __expf(0.5f * bv0[n]), bm0[n]); return; }
    i -= B0_N;
    if (i < B1_N) { int n = i % D2; bias1[i] = fmaf(be1[i], __expf(0.5f * bv1[n]), bm1[n]); return; }
    i -= B1_N;
    if (i < BL_N) { int o = i % DOUT; biasl[i] = fmaf(bel[i], __expf(0.5f * bvl[o]), bml[o]); return; }
}

// ------- barrier-free-per-wave fused-sampling GEMM, K-split across 2 waves -------
// One 128-thread block (2 waves) per 64(M) x 32(N) output tile. N fixed at 512.
// Wave w owns k-tiles [w*KTH, min(KT,(w+1)*KTH)); partials combined via LDS.
__global__ __launch_bounds__(128) void gemm_wave(
    const unsigned short* __restrict__ A, int lda, long aStride,   // bf16 [.][64][lda]
    const float* __restrict__ eps, long eStride,                   // fp32 [S][Kvalid][512]
    const unsigned int* __restrict__ psm,                          // packed [Kvalid][512]
    int KT, int Kvalid,                                            // K = KT*32 (A padded)
    const float* __restrict__ bias,                                // [S][512]
    void* __restrict__ outp, int outBf16)                          // [S][64][512]
{
    __shared__ unsigned short smB[2][32 * RSB];   // 2x2560 B, wave-private staging
    __shared__ float psum[32 * PS];               // 9216 B, partial-sum exchange

    const int bx = blockIdx.x;
    const int s  = bx >> 4;            // 16 n-tiles of 32 per sample
    const int n0 = (bx & 15) << 5;
    const int l  = threadIdx.x & 63;   // lane 0..63
    const int w  = threadIdx.x >> 6;   // wave 0/1
    const int fr = l & 15, quad = l >> 4;
    const int kg = l >> 3;             // 0..7 : k-subgroup (4 rows each)
    const int ng = l & 7;              // 0..7 : n-group of 4 floats

    const unsigned short* aP = A + (long)s * aStride + (long)fr * lda + quad * 8;
    const float* eB        = eps + (long)s * eStride + n0 + 4 * ng;
    const unsigned int* pB = psm + n0 + 4 * ng;
    unsigned short* myB    = &smB[w][0];

    f32x4 acc[4][2] = {};

    float4 ea0[4], ea1[4];
    uint4  pa0[4], pa1[4], aa0[4], aa1[4];

    auto loadAll = [&](int kt, float4* ea, uint4* pa, uint4* aa) {
        const int kb = kt * 32;
#pragma unroll
        for (int mi = 0; mi < 4; ++mi)
            aa[mi] = *reinterpret_cast<const uint4*>(aP + (long)(mi * 16) * lda + kb);
#pragma unroll
        for (int j = 0; j < 4; ++j) {
            const int row = kb + 4 * kg + j;
            const bool ok = row < Kvalid;
            const long off = (long)(ok ? row : 0) * 512;   // clamp: never OOB
            float4 e = *reinterpret_cast<const float4*>(eB + off);
            uint4  p = *reinterpret_cast<const uint4*>(pB + off);
            if (!ok) { e = float4{0.f, 0.f, 0.f, 0.f}; p = uint4{0u, 0u, 0u, 0u}; }
            ea[j] = e; pa[j] = p;
        }
    };

    // transform + in-register transpose + LDS write ([n][k] layout, wave-private)
    auto stage = [&](const float4* ea, const uint4* pa) {
        float wv[4][4];   // wv[j][i] = W[k=4kg+j][n=4ng+i]
#pragma unroll
        for (int j = 0; j < 4; ++j) {
            wv[j][0] = fmaf(ea[j].x, bf_hi(pa[j].x), bf_lo(pa[j].x));
            wv[j][1] = fmaf(ea[j].y, bf_hi(pa[j].y), bf_lo(pa[j].y));
            wv[j][2] = fmaf(ea[j].z, bf_hi(pa[j].z), bf_lo(pa[j].z));
            wv[j][3] = fmaf(ea[j].w, bf_hi(pa[j].w), bf_lo(pa[j].w));
        }
#pragma unroll
        for (int i = 0; i < 4; ++i) {
            uint2 d;
            d.x = (unsigned)f2bf(wv[0][i]) | ((unsigned)f2bf(wv[1][i]) << 16);
            d.y = (unsigned)f2bf(wv[2][i]) | ((unsigned)f2bf(wv[3][i]) << 16);
            *reinterpret_cast<uint2*>(&myB[(4 * ng + i) * RSB + 4 * kg]) = d;  // 8B-aligned
        }
    };

    auto compute = [&](const uint4* aa) {
        FragU bf0, bf1;   // B[k=quad*8+j][n=fr] : contiguous 16 B in [n][k] rows
        bf0.q = *reinterpret_cast<const uint4*>(&myB[fr * RSB + quad * 8]);
        bf1.q = *reinterpret_cast<const uint4*>(&myB[(16 + fr) * RSB + quad * 8]);
#pragma unroll
        for (int mi = 0; mi < 4; ++mi) {
            FragU af; af.q = aa[mi];
            acc[mi][0] = __builtin_amdgcn_mfma_f32_16x16x32_bf16(af.v, bf0.v, acc[mi][0], 0, 0, 0);
            acc[mi][1] = __builtin_amdgcn_mfma_f32_16x16x32_bf16(af.v, bf1.v, acc[mi][1], 0, 0, 0);
        }
    };

    // per-wave k-tile range
    const int KTH = (KT + 1) >> 1;
    const int tB  = w * KTH;
    const int tE  = (tB + KTH < KT) ? (tB + KTH) : KT;

    // ping-pong register pipeline; DS ops per-wave in-order -> no barrier needed
    loadAll(tB, ea0, pa0, aa0);
    int kt = tB;
    for (; kt + 2 <= tE; kt += 2) {
        loadAll(kt + 1, ea1, pa1, aa1);
        stage(ea0, pa0);
        compute(aa0);
        if (kt + 2 < tE) loadAll(kt + 2, ea0, pa0, aa0);
        stage(ea1, pa1);
        compute(aa1);
    }
    if (kt < tE) { stage(ea0, pa0); compute(aa0); }

    // ---- combine partials: wave1 -> LDS, wave0 adds ----
    if (w == 1) {
#pragma unroll
        for (int mi = 0; mi < 4; ++mi) {
#pragma unroll
            for (int ni = 0; ni < 2; ++ni) {
                const int col = ni * 16 + fr;
                const int row = mi * 16 + quad * 4;
                *reinterpret_cast<f32x4*>(&psum[col * PS + row]) = acc[mi][ni];
            }
        }
    }
    __syncthreads();
    if (w == 0) {
        // epilogue: add partial + bias + relu
        const float bv0v = bias[(long)s * 512 + n0 + fr];
        const float bv1v = bias[(long)s * 512 + n0 + 16 + fr];
        const long outBase = (long)s * BATCH * 512;
#pragma unroll
        for (int mi = 0; mi < 4; ++mi) {
#pragma unroll
            for (int ni = 0; ni < 2; ++ni) {
                const int col = ni * 16 + fr;
                const int row4 = mi * 16 + quad * 4;
                const f32x4 part = *reinterpret_cast<const f32x4*>(&psum[col * PS + row4]);
                const float bv = ni ? bv1v : bv0v;
                const int ocol = n0 + col;
#pragma unroll
                for (int r = 0; r < 4; ++r) {
                    const int row = row4 + r;
                    float v = fmaxf(acc[mi][ni][r] + part[r] + bv, 0.f);
                    const long idx = outBase + (long)row * 512 + ocol;
                    if (outBf16) ((unsigned short*)outp)[idx] = f2bf(v);
                    else         ((float*)outp)[idx] = v;
                }
            }
        }
    }
}

// ---------------- final layer: [64,512] @ [512,10] + bias, fp32 VALU ----------------
__global__ __launch_bounds__(320) void last_layer(
    const float* __restrict__ act2,   // [S][64][512]
    const float* __restrict__ wel,    // [S][512][10]
    const float* __restrict__ sigmal, // [512][10]
    const float* __restrict__ wml,    // [512][10]
    const float* __restrict__ biasl,  // [S][10]
    float* __restrict__ out)          // [S][64][10]
{
    __shared__ float smW[D2 * DOUT];  // 20 KB
    const int s = blockIdx.x;
    const int t = threadIdx.x;
    const float* we = wel + (long)s * D2 * DOUT;
    for (int i = t; i < D2 * DOUT; i += 320)
        smW[i] = fmaf(we[i], sigmal[i], wml[i]);
    __syncthreads();

    const int m  = t / 5;
    const int op = t % 5;
    const float* a = act2 + ((long)s * BATCH + m) * D2;
    float acc0 = 0.f, acc1 = 0.f;
#pragma unroll 4
    for (int k = 0; k < D2; k += 4) {
        float4 av = *reinterpret_cast<const float4*>(a + k);
        acc0 = fmaf(av.x, smW[(k + 0) * DOUT + op], acc0);
        acc0 = fmaf(av.y, smW[(k + 1) * DOUT + op], acc0);
        acc0 = fmaf(av.z, smW[(k + 2) * DOUT + op], acc0);
        acc0 = fmaf(av.w, smW[(k + 3) * DOUT + op], acc0);
        acc1 = fmaf(av.x, smW[(k + 0) * DOUT + op + 5], acc1);
        acc1 = fmaf(av.y, smW[(k + 1) * DOUT + op + 5], acc1);
        acc1 = fmaf(av.z, smW[(k + 2) * DOUT + op + 5], acc1);
        acc1 = fmaf(av.w, smW[(k + 3) * DOUT + op + 5], acc1);
    }
    const long ob = ((long)s * BATCH + m) * DOUT;
    out[ob + op]     = acc0 + biasl[s * DOUT + op];
    out[ob + op + 5] = acc1 + biasl[s * DOUT + op + 5];
}

extern "C" void kernel_launch(void* const* d_in, const int* in_sizes, int n_in,
                              void* d_out, int out_size, void* d_ws, size_t ws_size,
                              hipStream_t stream)
{
    const float* inputs = (const float*)d_in[0];
    // d_in[1] = task_id (unused)
    const float* wm0 = (const float*)d_in[2];
    const float* wv0 = (const float*)d_in[3];
    const float* bm0 = (const float*)d_in[4];
    const float* bv0 = (const float*)d_in[5];
    const float* wm1 = (const float*)d_in[6];
    const float* wv1 = (const float*)d_in[7];
    const float* bm1 = (const float*)d_in[8];
    const float* bv1 = (const float*)d_in[9];
    const float* wml = (const float*)d_in[10];
    const float* wvl = (const float*)d_in[11];
    const float* bml = (const float*)d_in[12];
    const float* bvl = (const float*)d_in[13];
    const float* we0 = (const float*)d_in[14];
    const float* be0 = (const float*)d_in[15];
    const float* we1 = (const float*)d_in[16];
    const float* be1 = (const float*)d_in[17];
    const float* wel = (const float*)d_in[18];
    const float* bel = (const float*)d_in[19];

    // workspace carve (~23 MB, all chunks 16B-aligned)
    char* w = (char*)d_ws;
    unsigned short* Xb  = (unsigned short*)w; w += (size_t)XB_N * 2;
    unsigned int* psm0  = (unsigned int*)w;   w += (size_t)PS0_N * 4;
    unsigned int* psm1  = (unsigned int*)w;   w += (size_t)PS1_N * 4;
    float* sigmal = (float*)w; w += (size_t)SGL_N * 4;
    float* bias0  = (float*)w; w += (size_t)B0_N * 4;
    float* bias1  = (float*)w; w += (size_t)B1_N * 4;
    float* biasl  = (float*)w; w += (size_t)BL_N * 4;
    unsigned short* act1 = (unsigned short*)w; w += (size_t)NSAMP * BATCH * D1 * 2;
    float* act2 = (float*)w; w += (size_t)NSAMP * BATCH * D2 * 4;

    prep<<<dim3((PREP_TOTAL + 255) / 256), 256, 0, stream>>>(
        inputs, wv0, wm0, wv1, wm1, wvl,
        be0, bv0, bm0, be1, bv1, bm1, bel, bvl, bml,
        Xb, psm0, psm1, sigmal, bias0, bias1, biasl);

    // layer 0: A = Xb shared across samples (aStride=0), K = 800 padded, Kvalid=784
    gemm_wave<<<dim3(NSAMP * 16), 128, 0, stream>>>(
        Xb, K0PAD, 0L, we0, (long)D0 * D1, psm0,
        K0PAD / 32, D0, bias0, (void*)act1, 1);

    // layer 1: K = 512 exact
    gemm_wave<<<dim3(NSAMP * 16), 128, 0, stream>>>(
        act1, D1, (long)BATCH * D1, we1, (long)D1 * D2, psm1,
        D1 / 32, D1, bias1, (void*)act2, 0);

    last_layer<<<dim3(NSAMP), 320, 0, stream>>>(
        act2, wel, sigmal, wml, biasl, (float*)d_out);
}

// Round 3
// 383.364 us; speedup vs baseline: 1.0624x; 1.0497x over previous
//
#include <hip/hip_runtime.h>
#include <hip/hip_bf16.h>

// BNN MC-prediction: S=100 weight samples, batch 64, dims 784->512->512->10.
// R6 == R5 resubmit (container failed twice, no counters). Single change:
// barrier expressed as asm lgkmcnt(0) + __builtin_amdgcn_s_barrier() (the
// HW-verified 8-phase-template form) instead of a raw asm s_barrier blob,
// in case the opaque asm barrier broke compiler convergence bookkeeping.
//
// R5 theory (unchanged): R3->R4 showed dur invariant under 2x waves with
// identical VMEM bytes -> bottleneck is the per-CU VMEM return path (~5 TB/s
// aggregate = 80% of the m13 streaming ceiling), NOT HBM/VALU/MFMA/latency.
// Fix: 4 waves/block = 4 samples sharing one (n0, k-tile); psm tile (and
// layer-0's sample-independent A tile) staged cooperatively into double-
// buffered LDS once per block instead of once per wave -> 2x VMEM cut for
// layer 0, 1.33x for layer 1. lgkmcnt-only barrier keeps eps global loads
// in flight across the barrier (no vmcnt(0) drain).

typedef __bf16 bf16x8 __attribute__((ext_vector_type(8)));
typedef float f32x4 __attribute__((ext_vector_type(4)));

#define NSAMP 100
#define BATCH 64
#define D0 784
#define D1 512
#define D2 512
#define DOUT 10
#define K0PAD 800   // 784 padded to multiple of 32 (A side zero-padded)
#define RSB 40      // smB row stride in shorts (80 B rows)
#define PSW 36      // psmT row stride in words (144 B rows, 16B-aligned, spread banks)
#define ATS 40      // aT row stride in shorts (80 B rows)

__device__ __forceinline__ unsigned short f2bf(float f) {
    __bf16 b = (__bf16)f;
    return __builtin_bit_cast(unsigned short, b);
}
// packed dword: high16 = bf16(sigma), low16 = bf16(mean)
__device__ __forceinline__ float bf_hi(unsigned int u) {
    return __builtin_bit_cast(float, u & 0xffff0000u);
}
__device__ __forceinline__ float bf_lo(unsigned int u) {
    return __builtin_bit_cast(float, u << 16);
}

union FragU { uint4 q; bf16x8 v; };

// drain own LDS ops, then HW barrier. vmcnt NOT drained -> eps register
// pipeline survives the barrier. builtin keeps compiler convergence info.
__device__ __forceinline__ void lds_barrier() {
    asm volatile("s_waitcnt lgkmcnt(0)" ::: "memory");
    __builtin_amdgcn_s_barrier();
}

// ---------------- precompute ----------------
#define XB_N   (BATCH * K0PAD)
#define PS0_N  (D0 * D1)
#define PS1_N  (D1 * D2)
#define SGL_N  (D2 * DOUT)
#define B0_N   (NSAMP * D1)
#define B1_N   (NSAMP * D2)
#define BL_N   (NSAMP * DOUT)
#define PREP_TOTAL (XB_N + PS0_N + PS1_N + SGL_N + B0_N + B1_N + BL_N)

__global__ __launch_bounds__(256) void prep(
    const float* __restrict__ inputs,
    const float* __restrict__ wv0, const float* __restrict__ wm0,
    const float* __restrict__ wv1, const float* __restrict__ wm1,
    const float* __restrict__ wvl,
    const float* __restrict__ be0, const float* __restrict__ bv0, const float* __restrict__ bm0,
    const float* __restrict__ be1, const float* __restrict__ bv1, const float* __restrict__ bm1,
    const float* __restrict__ bel, const float* __restrict__ bvl, const float* __restrict__ bml,
    unsigned short* __restrict__ Xb,
    unsigned int* __restrict__ psm0, unsigned int* __restrict__ psm1,
    float* __restrict__ sigmal,
    float* __restrict__ bias0, float* __restrict__ bias1, float* __restrict__ biasl)
{
    int i = blockIdx.x * 256 + threadIdx.x;
    if (i < XB_N) {
        int m = i / K0PAD, k = i % K0PAD;
        float v = (k < D0) ? inputs[m * D0 + k] : 0.f;
        Xb[i] = f2bf(v);
        return;
    }
    i -= XB_N;
    if (i < PS0_N) {
        unsigned int sg = f2bf(__expf(0.5f * wv0[i]));
        unsigned int mn = f2bf(wm0[i]);
        psm0[i] = (sg << 16) | mn;
        return;
    }
    i -= PS0_N;
    if (i < PS1_N) {
        unsigned int sg = f2bf(__expf(0.5f * wv1[i]));
        unsigned int mn = f2bf(wm1[i]);
        psm1[i] = (sg << 16) | mn;
        return;
    }
    i -= PS1_N;
    if (i < SGL_N) { sigmal[i] = __expf(0.5f * wvl[i]); return; }
    i -= SGL_N;
    if (i < B0_N) { int n = i % D1; bias0[i] = fmaf(be0[i], __expf(0.5f * bv0[n]), bm0[n]); return; }
    i -= B0_N;
    if (i < B1_N) { int n = i % D2; bias1[i] = fmaf(be1[i], __expf(0.5f * bv1[n]), bm1[n]); return; }
    i -= B1_N;
    if (i < BL_N) { int o = i % DOUT; biasl[i] = fmaf(bel[i], __expf(0.5f * bvl[o]), bml[o]); return; }
}

// ------- multi-sample fused-sampling GEMM: 4 waves = 4 samples, shared tiles -------
// Block: 256 threads. Wave w handles sample sg*4+w, output 64(M) x 32(N), full K.
// psm k-tile (and layer-0 A k-tile) staged once per block into double-buffered LDS.
__global__ __launch_bounds__(256) void gemm_ms(
    const unsigned short* __restrict__ A, int lda, long aStride, int aShared,
    const float* __restrict__ eps, long eStride,                   // fp32 [S][Kvalid][512]
    const unsigned int* __restrict__ psm,                          // packed [Kvalid][512]
    int KT, int Kvalid,                                            // K = KT*32 (A padded)
    const float* __restrict__ bias,                                // [S][512]
    void* __restrict__ outp, int outBf16)                          // [S][64][512]
{
    __shared__ unsigned int   psmT[2][32 * PSW];   // 9216 B, block-shared, dbuf
    __shared__ unsigned short aT[2][64 * ATS];     // 10240 B, block-shared (layer-0 only)
    __shared__ unsigned short smB[4][32 * RSB];    // 10240 B, wave-private staging

    const int bx = blockIdx.x;
    const int sg = bx >> 4;            // sample group 0..24
    const int n0 = (bx & 15) << 5;     // 16 n-tiles of 32
    const int t  = threadIdx.x;
    const int w  = t >> 6;             // wave 0..3
    const int l  = t & 63;
    const int s  = sg * 4 + w;         // this wave's sample
    const int fr = l & 15, quad = l >> 4;
    const int kg = l >> 3;             // 0..7 : k-subgroup (4 rows each)
    const int ng = l & 7;              // 0..7 : n-group of 4 floats

    // block-wide staging roles
    const int prow = t >> 3, pcol = (t & 7) << 2;   // psm: 32 rows x 8x(4 uints)
    const int arow = t >> 2, acol = (t & 3) << 3;   // A:   64 rows x 4x(8 shorts)

    const unsigned short* aP = A + (long)s * aStride + (long)fr * lda + quad * 8;
    const float* eB = eps + (long)s * eStride + n0 + 4 * ng;

    f32x4 acc[4][2] = {};
    float4 ea0[4], ea1[4];
    uint4  aa0[4], aa1[4];             // layer-1 per-wave A frags (ping-pong)
    uint4  pReg, aReg;                 // cooperative staging regs

    auto issueStage = [&](int kt) {
        const int kb = kt * 32;
        int pr = kb + prow; if (pr >= Kvalid) pr = Kvalid - 1;  // clamp; A pad zeroes it out
        pReg = *reinterpret_cast<const uint4*>(psm + (long)pr * 512 + n0 + pcol);
        if (aShared)
            aReg = *reinterpret_cast<const uint4*>(A + (long)arow * lda + kb + acol);
    };
    auto writeStage = [&](int buf) {
        *reinterpret_cast<uint4*>(&psmT[buf][prow * PSW + pcol]) = pReg;
        if (aShared)
            *reinterpret_cast<uint4*>(&aT[buf][arow * ATS + acol]) = aReg;
    };
    auto issueA = [&](int kt, uint4* aa) {   // layer-1: per-wave (per-sample) A frags
        const int kb = kt * 32;
#pragma unroll
        for (int mi = 0; mi < 4; ++mi)
            aa[mi] = *reinterpret_cast<const uint4*>(aP + (long)(mi * 16) * lda + kb);
    };
    auto issueEps = [&](int kt, float4* ea) {
        const int kb = kt * 32;
#pragma unroll
        for (int j = 0; j < 4; ++j) {
            const int row = kb + 4 * kg + j;
            const bool ok = row < Kvalid;
            const long off = (long)(ok ? row : 0) * 512;   // clamp: never OOB
            float4 e = *reinterpret_cast<const float4*>(eB + off);
            if (!ok) e = float4{0.f, 0.f, 0.f, 0.f};
            ea[j] = e;
        }
    };

    // transform + in-register transpose + wave-private smB + MFMA
    auto computeTile = [&](int buf, const float4* ea, const uint4* aa) {
        uint4 p[4];
#pragma unroll
        for (int j = 0; j < 4; ++j)
            p[j] = *reinterpret_cast<const uint4*>(&psmT[buf][(4 * kg + j) * PSW + 4 * ng]);
        float wv[4][4];   // wv[j][i] = W[k=4kg+j][n=4ng+i]
#pragma unroll
        for (int j = 0; j < 4; ++j) {
            wv[j][0] = fmaf(ea[j].x, bf_hi(p[j].x), bf_lo(p[j].x));
            wv[j][1] = fmaf(ea[j].y, bf_hi(p[j].y), bf_lo(p[j].y));
            wv[j][2] = fmaf(ea[j].z, bf_hi(p[j].z), bf_lo(p[j].z));
            wv[j][3] = fmaf(ea[j].w, bf_hi(p[j].w), bf_lo(p[j].w));
        }
#pragma unroll
        for (int i = 0; i < 4; ++i) {
            uint2 d;
            d.x = (unsigned)f2bf(wv[0][i]) | ((unsigned)f2bf(wv[1][i]) << 16);
            d.y = (unsigned)f2bf(wv[2][i]) | ((unsigned)f2bf(wv[3][i]) << 16);
            *reinterpret_cast<uint2*>(&smB[w][(4 * ng + i) * RSB + 4 * kg]) = d;
        }
        FragU bf0, bf1;   // B[k=quad*8+j][n=fr]
        bf0.q = *reinterpret_cast<const uint4*>(&smB[w][fr * RSB + quad * 8]);
        bf1.q = *reinterpret_cast<const uint4*>(&smB[w][(16 + fr) * RSB + quad * 8]);
#pragma unroll
        for (int mi = 0; mi < 4; ++mi) {
            FragU af;
            if (aShared)
                af.q = *reinterpret_cast<const uint4*>(&aT[buf][(fr + mi * 16) * ATS + quad * 8]);
            else
                af.q = aa[mi];
            acc[mi][0] = __builtin_amdgcn_mfma_f32_16x16x32_bf16(af.v, bf0.v, acc[mi][0], 0, 0, 0);
            acc[mi][1] = __builtin_amdgcn_mfma_f32_16x16x32_bf16(af.v, bf1.v, acc[mi][1], 0, 0, 0);
        }
    };

    // prologue: tile 0 -> buf 0
    issueStage(0);
    if (!aShared) issueA(0, aa0);
    issueEps(0, ea0);
    writeStage(0);
    lds_barrier();

    int kt = 0;
    while (kt < KT) {
        {   // even iter: compute buf0, stage tile kt+1 -> buf1
            const int kn = (kt + 1 < KT) ? kt + 1 : kt;
            issueStage(kn);
            if (!aShared) issueA(kn, aa1);
            issueEps(kn, ea1);
            computeTile(0, ea0, aa0);
            writeStage(1);
            lds_barrier();
        }
        ++kt;
        if (kt >= KT) break;
        {   // odd iter: compute buf1, stage tile kt+1 -> buf0
            const int kn = (kt + 1 < KT) ? kt + 1 : kt;
            issueStage(kn);
            if (!aShared) issueA(kn, aa0);
            issueEps(kn, ea0);
            computeTile(1, ea1, aa1);
            writeStage(0);
            lds_barrier();
        }
        ++kt;
    }

    // epilogue: bias + relu + store (per wave, own sample)
    const float bv0v = bias[(long)s * 512 + n0 + fr];
    const float bv1v = bias[(long)s * 512 + n0 + 16 + fr];
    const long outBase = (long)s * BATCH * 512;
#pragma unroll
    for (int mi = 0; mi < 4; ++mi) {
#pragma unroll
        for (int ni = 0; ni < 2; ++ni) {
            const float bv = ni ? bv1v : bv0v;
            const int col = n0 + ni * 16 + fr;
#pragma unroll
            for (int r = 0; r < 4; ++r) {
                const int row = mi * 16 + quad * 4 + r;
                float v = fmaxf(acc[mi][ni][r] + bv, 0.f);
                const long idx = outBase + (long)row * 512 + col;
                if (outBf16) ((unsigned short*)outp)[idx] = f2bf(v);
                else         ((float*)outp)[idx] = v;
            }
        }
    }
}

// ---------------- final layer: [64,512] @ [512,10] + bias, fp32 VALU ----------------
__global__ __launch_bounds__(320) void last_layer(
    const float* __restrict__ act2,   // [S][64][512]
    const float* __restrict__ wel,    // [S][512][10]
    const float* __restrict__ sigmal, // [512][10]
    const float* __restrict__ wml,    // [512][10]
    const float* __restrict__ biasl,  // [S][10]
    float* __restrict__ out)          // [S][64][10]
{
    __shared__ float smW[D2 * DOUT];  // 20 KB
    const int s = blockIdx.x;
    const int t = threadIdx.x;
    const float* we = wel + (long)s * D2 * DOUT;
    for (int i = t; i < D2 * DOUT; i += 320)
        smW[i] = fmaf(we[i], sigmal[i], wml[i]);
    __syncthreads();

    const int m  = t / 5;
    const int op = t % 5;
    const float* a = act2 + ((long)s * BATCH + m) * D2;
    float acc0 = 0.f, acc1 = 0.f;
#pragma unroll 4
    for (int k = 0; k < D2; k += 4) {
        float4 av = *reinterpret_cast<const float4*>(a + k);
        acc0 = fmaf(av.x, smW[(k + 0) * DOUT + op], acc0);
        acc0 = fmaf(av.y, smW[(k + 1) * DOUT + op], acc0);
        acc0 = fmaf(av.z, smW[(k + 2) * DOUT + op], acc0);
        acc0 = fmaf(av.w, smW[(k + 3) * DOUT + op], acc0);
        acc1 = fmaf(av.x, smW[(k + 0) * DOUT + op + 5], acc1);
        acc1 = fmaf(av.y, smW[(k + 1) * DOUT + op + 5], acc1);
        acc1 = fmaf(av.z, smW[(k + 2) * DOUT + op + 5], acc1);
        acc1 = fmaf(av.w, smW[(k + 3) * DOUT + op + 5], acc1);
    }
    const long ob = ((long)s * BATCH + m) * DOUT;
    out[ob + op]     = acc0 + biasl[s * DOUT + op];
    out[ob + op + 5] = acc1 + biasl[s * DOUT + op + 5];
}

extern "C" void kernel_launch(void* const* d_in, const int* in_sizes, int n_in,
                              void* d_out, int out_size, void* d_ws, size_t ws_size,
                              hipStream_t stream)
{
    const float* inputs = (const float*)d_in[0];
    // d_in[1] = task_id (unused)
    const float* wm0 = (const float*)d_in[2];
    const float* wv0 = (const float*)d_in[3];
    const float* bm0 = (const float*)d_in[4];
    const float* bv0 = (const float*)d_in[5];
    const float* wm1 = (const float*)d_in[6];
    const float* wv1 = (const float*)d_in[7];
    const float* bm1 = (const float*)d_in[8];
    const float* bv1 = (const float*)d_in[9];
    const float* wml = (const float*)d_in[10];
    const float* wvl = (const float*)d_in[11];
    const float* bml = (const float*)d_in[12];
    const float* bvl = (const float*)d_in[13];
    const float* we0 = (const float*)d_in[14];
    const float* be0 = (const float*)d_in[15];
    const float* we1 = (const float*)d_in[16];
    const float* be1 = (const float*)d_in[17];
    const float* wel = (const float*)d_in[18];
    const float* bel = (const float*)d_in[19];

    // workspace carve (~23 MB, all chunks 16B-aligned)
    char* w = (char*)d_ws;
    unsigned short* Xb  = (unsigned short*)w; w += (size_t)XB_N * 2;
    unsigned int* psm0  = (unsigned int*)w;   w += (size_t)PS0_N * 4;
    unsigned int* psm1  = (unsigned int*)w;   w += (size_t)PS1_N * 4;
    float* sigmal = (float*)w; w += (size_t)SGL_N * 4;
    float* bias0  = (float*)w; w += (size_t)B0_N * 4;
    float* bias1  = (float*)w; w += (size_t)B1_N * 4;
    float* biasl  = (float*)w; w += (size_t)BL_N * 4;
    unsigned short* act1 = (unsigned short*)w; w += (size_t)NSAMP * BATCH * D1 * 2;
    float* act2 = (float*)w; w += (size_t)NSAMP * BATCH * D2 * 4;

    prep<<<dim3((PREP_TOTAL + 255) / 256), 256, 0, stream>>>(
        inputs, wv0, wm0, wv1, wm1, wvl,
        be0, bv0, bm0, be1, bv1, bm1, bel, bvl, bml,
        Xb, psm0, psm1, sigmal, bias0, bias1, biasl);

    // layer 0: A = Xb shared across samples (aStride=0, aShared=1), K=800 pad, Kvalid=784
    gemm_ms<<<dim3((NSAMP / 4) * 16), 256, 0, stream>>>(
        Xb, K0PAD, 0L, 1, we0, (long)D0 * D1, psm0,
        K0PAD / 32, D0, bias0, (void*)act1, 1);

    // layer 1: per-sample A (aShared=0), K = 512 exact
    gemm_ms<<<dim3((NSAMP / 4) * 16), 256, 0, stream>>>(
        act1, D1, (long)BATCH * D1, 0, we1, (long)D1 * D2, psm1,
        D1 / 32, D1, bias1, (void*)act2, 0);

    last_layer<<<dim3(NSAMP), 320, 0, stream>>>(
        act2, wel, sigmal, wml, biasl, (float*)d_out);
}